// Round 2
// baseline (445.113 us; speedup 1.0000x reference)
//
#include <hip/hip_runtime.h>

// LoRA forward, fused, all fp32:
//   out[m,n] = 2 * sum_r (sum_k x[m,k] * B[k,r]) * A[r,n]
// x: [16384, 4096] f32, B: [4096, 8] f32, A: [8, 4096] f32, out: [16384, 4096] f32.
// Memory-bound: 256 MB read (x) + 256 MB write (out); A/B are L2-resident.

#define NT      256
#define ROWS    16
#define KDIM    4096
#define NDIM    4096
#define M_TOTAL 16384

typedef __attribute__((ext_vector_type(4))) float float4v;

__global__ __launch_bounds__(NT, 2) void lora_fused(
    const float* __restrict__ x,
    const float* __restrict__ A,
    const float* __restrict__ B,
    float* __restrict__ out)
{
    __shared__ float part[ROWS][4][8];  // per-wave rank partials
    __shared__ float tl[ROWS][8];       // final 2*t[row][r]

    const int t = threadIdx.x;
    const int wave = t >> 6;
    const long m_base = (long)blockIdx.x * ROWS;

    // frag[j][r]: phase 1 = B[k(j)][r]; phase 2 (reused) = A[r][n(j)].
    // j = 4*q + i  ->  k(j) = n(j) = q*1024 + 4*t + i   (q,i in 0..3)
    float frag[16][8];

    {   // B fragment: 16 rows of B, each 8 f32 = two float4.
        const float4v* Bv = (const float4v*)B;
#pragma unroll
        for (int q = 0; q < 4; ++q)
#pragma unroll
            for (int i = 0; i < 4; ++i) {
                const int k = q * 1024 + 4 * t + i;
                float4v b0 = Bv[2 * k];
                float4v b1 = Bv[2 * k + 1];
                const int j = 4 * q + i;
#pragma unroll
                for (int r = 0; r < 4; ++r) {
                    frag[j][r]     = b0[r];
                    frag[j][4 + r] = b1[r];
                }
            }
    }

    // ---------------- Phase 1: t = x @ B ----------------
    float4v c[4];
    {
        const float4v* xr = (const float4v*)(x + m_base * KDIM);
#pragma unroll
        for (int q = 0; q < 4; ++q) c[q] = xr[q * 256 + t];
    }
#pragma unroll 1
    for (int rr = 0; rr < ROWS; ++rr) {
        // software prefetch next row (wraps harmlessly on last iter)
        const int rn = (rr + 1) & (ROWS - 1);
        const float4v* xrn = (const float4v*)(x + (m_base + rn) * KDIM);
        float4v n0 = xrn[t];
        float4v n1 = xrn[256 + t];
        float4v n2 = xrn[512 + t];
        float4v n3 = xrn[768 + t];

        float acc[8];
#pragma unroll
        for (int r = 0; r < 8; ++r) acc[r] = 0.0f;
#pragma unroll
        for (int q = 0; q < 4; ++q)
#pragma unroll
            for (int i = 0; i < 4; ++i) {
                const float xv = c[q][i];
                const int j = 4 * q + i;
#pragma unroll
                for (int r = 0; r < 8; ++r)
                    acc[r] = fmaf(xv, frag[j][r], acc[r]);
            }

        // 64-lane butterfly allreduce of the 8 rank partials
#pragma unroll
        for (int off = 32; off > 0; off >>= 1)
#pragma unroll
            for (int r = 0; r < 8; ++r)
                acc[r] += __shfl_xor(acc[r], off, 64);

        if ((t & 63) == 0) {
#pragma unroll
            for (int r = 0; r < 8; ++r) part[rr][wave][r] = acc[r];
        }
        c[0] = n0; c[1] = n1; c[2] = n2; c[3] = n3;
    }
    __syncthreads();
    if (t < ROWS * 8) {
        const int rr = t >> 3, r = t & 7;
        tl[rr][r] = 2.0f * (part[rr][0][r] + part[rr][1][r] +
                            part[rr][2][r] + part[rr][3][r]);
    }

    {   // A fragment into the same register array
        const float4v* Av = (const float4v*)A;
#pragma unroll
        for (int r = 0; r < 8; ++r)
#pragma unroll
            for (int q = 0; q < 4; ++q) {
                float4v a = Av[r * 1024 + q * 256 + t];
#pragma unroll
                for (int i = 0; i < 4; ++i)
                    frag[4 * q + i][r] = a[i];
            }
    }
    __syncthreads();

    // ---------------- Phase 2: out = (2t) @ A ----------------
#pragma unroll 1
    for (int rr = 0; rr < ROWS; ++rr) {
        float tv[8];
#pragma unroll
        for (int r = 0; r < 8; ++r) tv[r] = tl[rr][r];  // LDS broadcast

        float4v* orow = (float4v*)(out + (m_base + rr) * NDIM);
#pragma unroll
        for (int q = 0; q < 4; ++q) {
            float4v o;
#pragma unroll
            for (int i = 0; i < 4; ++i) {
                float s = 0.0f;
#pragma unroll
                for (int r = 0; r < 8; ++r)
                    s = fmaf(tv[r], frag[4 * q + i][r], s);
                o[i] = s;
            }
            orow[q * 256 + t] = o;
        }
    }
}

extern "C" void kernel_launch(void* const* d_in, const int* in_sizes, int n_in,
                              void* d_out, int out_size, void* d_ws, size_t ws_size,
                              hipStream_t stream) {
    const float* x = (const float*)d_in[0];  // [4,4096,4096] -> [16384,4096]
    const float* A = (const float*)d_in[1];  // [8,4096]
    const float* B = (const float*)d_in[2];  // [4096,8]
    float* out = (float*)d_out;

    (void)in_sizes; (void)n_in; (void)out_size; (void)d_ws; (void)ws_size;

    dim3 grid(M_TOTAL / ROWS);
    lora_fused<<<grid, NT, 0, stream>>>(x, A, B, out);
}